// Round 4
// baseline (318.567 us; speedup 1.0000x reference)
//
#include <hip/hip_runtime.h>

// ---------------- problem constants ----------------
#define BATCH     16
#define T_LEN     480000
#define PAD       512
#define TPAD      481024      // T_LEN + 2*PAD
#define HOP       256
#define NFRAMES   1876        // (TPAD - NFFT)/HOP + 1
#define FRPAD     1920        // frames padded to 15 blocks of 128 per batch
#define NOUTROW   1026        // 513 freqs * 2 (re,im interleaved)
#define KTOT      1024
#define NCOLS     1152        // padded B columns: 9 tiles of 128 (cols >=1026 are zero)

// ---------------- GEMM tile config ----------------
#define BM        128
#define BN        128
#define BK        32
#define XPSTRIDE  493568      // padded xp row stride (zero tail covers frame 1919 reads)

typedef __attribute__((ext_vector_type(8))) short short8;
typedef __attribute__((ext_vector_type(4))) float floatx4;

__device__ __forceinline__ unsigned short f2bf(float f) {
  union { float f; unsigned int u; } v; v.f = f;
  unsigned int u = v.u;
  return (unsigned short)((u + 0x7FFFu + ((u >> 16) & 1u)) >> 16); // RNE
}

// Reflect-padded signal as bf16, row stride XPSTRIDE, tail zero-filled.
__global__ __launch_bounds__(256) void build_xp(const float* __restrict__ x,
                                                unsigned short* __restrict__ xp) {
  const int i = blockIdx.x * 256 + threadIdx.x;   // [0, XPSTRIDE)
  const int b = blockIdx.y;
  unsigned short v = 0;
  if (i < TPAD) {
    int j = i - PAD;
    if (j < 0) j = -j;                             // left reflect
    if (j >= T_LEN) j = 2 * T_LEN - 2 - j;         // right reflect
    v = f2bf(x[(size_t)b * T_LEN + j]);
  }
  xp[(size_t)b * XPSTRIDE + i] = v;
}

// Basis matrix bmat[jcol][k], jcol in [0,1152):
//   jcol = 2f   -> cos(2*pi/1024 * f * k) * w[k]
//   jcol = 2f+1 -> -sin(2*pi/1024 * f * k) * w[k]
// jcol=1024/1025 fall out exactly (f=512 -> (-1)^k, 0); jcol>=1026 -> 0.
__global__ __launch_bounds__(256) void build_bmat(const float* __restrict__ win,
                                                  unsigned short* __restrict__ bm) {
  const int k = blockIdx.x * 256 + threadIdx.x;   // [0,1024)
  const int j = blockIdx.y;                       // [0,1152)
  unsigned short o = 0;
  if (j < NOUTROW) {
    const int f = j >> 1;
    const int r = (f * k) & (KTOT - 1);           // exact arg reduction
    const float ang = (float)r * 6.1359231515e-3f;  // 2*pi/1024
    const float c = __cosf(ang), s = __sinf(ang);
    const float v = (j & 1) ? -s : c;
    o = f2bf(v * win[k]);
  }
  bm[(size_t)j * KTOT + k] = o;
}

// C[m][j] = sum_k xp[b][t*HOP + k] * bmat[j][k]
// Occupancy-first design: A frags direct from global (L1/L2-resident, register
// prefetched); B double-buffered in LDS (two distinct arrays), ONE barrier/iter
// with the staging load issued a full MFMA-phase before its vmcnt drain.
// LDS 16 KB, 4 blocks/CU.
__global__ __launch_bounds__(256, 4) void stft_gemm(const unsigned short* __restrict__ xp,
                                                    const unsigned short* __restrict__ bmat,
                                                    float* __restrict__ out) {
  __shared__ unsigned short Bs0[BN * BK];   // 8 KB
  __shared__ unsigned short Bs1[BN * BK];   // 8 KB

  const int tid  = threadIdx.x;
  const int lane = tid & 63;
  const int wv   = tid >> 6;
  const int wr   = wv >> 1, wc = wv & 1;   // 2x2 waves over 128x128
  const int bx   = blockIdx.x;             // [0,240)
  const int b    = bx / 15;
  const int t0   = (bx - b * 15) * BM;     // frame base, <=1792
  const int j0   = blockIdx.y * BN;        // [0,1152) step 128
  const int L    = lane & 15;
  const int quad = lane >> 4;

  // A fragment row pointers: row = t0 + wr*64 + t*16 + L, start chunk quad*8.
  // Per wave-instr: 16 rows x 64 B contiguous (4 quads) — dense gather, L1/L2.
  const unsigned short* arow[4];
#pragma unroll
  for (int t = 0; t < 4; ++t) {
    const int row = t0 + wr * 64 + t * 16 + L;
    arow[t] = xp + (size_t)b * XPSTRIDE + (size_t)row * HOP + quad * 8;
  }

  // B staging: thread owns chunks ci = p*256+tid (16 B each); col=ci>>2, kc=ci&3
  const unsigned short* bsrc[2];
#pragma unroll
  for (int p = 0; p < 2; ++p) {
    const int ci = p * 256 + tid;
    bsrc[p] = bmat + (size_t)(j0 + (ci >> 2)) * KTOT + (ci & 3) * 8;
  }

  // B fragment LDS offsets (elements): col n = wc*64 + t*16 + L, chunk quad
  int boff[4];
#pragma unroll
  for (int t = 0; t < 4; ++t) boff[t] = (wc * 64 + t * 16 + L) * BK + quad * 8;

  short8 af[4], afn[4];
  floatx4 acc[4][4] = {};

  auto stage = [&](unsigned short* dst, int kk) {
#pragma unroll
    for (int p = 0; p < 2; ++p) {
      const int ci = p * 256 + tid;
      __builtin_amdgcn_global_load_lds(
          (const __attribute__((address_space(1))) void*)(bsrc[p] + kk),
          (__attribute__((address_space(3))) void*)((char*)dst + ci * 16),
          16, 0, 0);
    }
  };
  auto aload = [&](int kk) {
#pragma unroll
    for (int t = 0; t < 4; ++t) afn[t] = *(const short8*)(arow[t] + kk);
  };
  auto compute = [&](const unsigned short* bb) {
    short8 bf[4];
#pragma unroll
    for (int t = 0; t < 4; ++t) bf[t] = *(const short8*)&bb[boff[t]];
#pragma unroll
    for (int ti = 0; ti < 4; ++ti)
#pragma unroll
      for (int tj = 0; tj < 4; ++tj)
        acc[ti][tj] = __builtin_amdgcn_mfma_f32_16x16x32_bf16(
            af[ti], bf[tj], acc[ti][tj], 0, 0, 0);
  };

  // ---- prologue: A(0) into regs, B(0) into Bs0 ----
#pragma unroll
  for (int t = 0; t < 4; ++t) af[t] = *(const short8*)arow[t];
  stage(Bs0, 0);
  __syncthreads();

  // ---- main loop: 16 double-iterations, one barrier per BK step ----
  for (int k0 = 0; k0 < KTOT; k0 += 2 * BK) {
    // phase 0: stage B(k0+32)->Bs1 + prefetch A(k0+32); compute on Bs0
    stage(Bs1, k0 + BK);
    aload(k0 + BK);
    compute(Bs0);
#pragma unroll
    for (int t = 0; t < 4; ++t) af[t] = afn[t];
    __syncthreads();

    // phase 1: stage B(k0+64)->Bs0 + prefetch A(k0+64); compute on Bs1
    const bool more = (k0 + 2 * BK) < KTOT;
    if (more) { stage(Bs0, k0 + 2 * BK); aload(k0 + 2 * BK); }
    compute(Bs1);
    if (more) {
#pragma unroll
      for (int t = 0; t < 4; ++t) af[t] = afn[t];
    }
    __syncthreads();
  }

  // ---- epilogue: D[row = quad*4 + i][col = L] per 16x16 tile ----
#pragma unroll
  for (int ti = 0; ti < 4; ++ti) {
    const int tb = t0 + wr * 64 + ti * 16 + quad * 4;
#pragma unroll
    for (int tj = 0; tj < 4; ++tj) {
      const int gj = j0 + wc * 64 + tj * 16 + L;
      if (gj < NOUTROW) {
#pragma unroll
        for (int i = 0; i < 4; ++i) {
          const int t = tb + i;
          if (t < NFRAMES)
            out[(size_t)(b * NFRAMES + t) * NOUTROW + gj] = acc[ti][tj][i];
        }
      }
    }
  }
}

extern "C" void kernel_launch(void* const* d_in, const int* in_sizes, int n_in,
                              void* d_out, int out_size, void* d_ws, size_t ws_size,
                              hipStream_t stream) {
  const float* x   = (const float*)d_in[0];   // (16, 480000) fp32
  const float* win = (const float*)d_in[1];   // (1024,) fp32
  float* out = (float*)d_out;                 // (16, 1876, 513, 2) fp32

  unsigned short* xp   = (unsigned short*)d_ws;                  // 16*493568 bf16 = 15.8 MB
  unsigned short* bmat = xp + (size_t)BATCH * XPSTRIDE;          // 1152*1024 bf16 = 2.36 MB

  build_xp  <<<dim3(XPSTRIDE / 256, BATCH), 256, 0, stream>>>(x, xp);
  build_bmat<<<dim3(KTOT / 256, NCOLS),     256, 0, stream>>>(win, bmat);
  stft_gemm <<<dim3(BATCH * (FRPAD / BM), NCOLS / BN), 256, 0, stream>>>(xp, bmat, out);
}

// Round 5
// 246.620 us; speedup vs baseline: 1.2917x; 1.2917x over previous
//
#include <hip/hip_runtime.h>

// ---------------- problem constants ----------------
#define BATCH     16
#define T_LEN     480000
#define PAD       512
#define TPAD      481024      // T_LEN + 2*PAD
#define HOP       256
#define NFRAMES   1876        // (TPAD - NFFT)/HOP + 1
#define FRPAD     1920        // frames padded to 15 blocks of 128 per batch
#define NOUTROW   1026        // 513 freqs * 2 (re,im interleaved)
#define KTOT      1024
#define NCOLS     1152        // padded B columns: 9 tiles of 128 (cols >=1026 are zero)

// ---------------- GEMM tile config ----------------
#define BM        128
#define BN        128
#define BK        32
#define XPSTRIDE  493568      // padded xp row stride (zero tail covers frame 1919 reads)

typedef __attribute__((ext_vector_type(8))) short short8;
typedef __attribute__((ext_vector_type(4))) float floatx4;

__device__ __forceinline__ unsigned short f2bf(float f) {
  union { float f; unsigned int u; } v; v.f = f;
  unsigned int u = v.u;
  return (unsigned short)((u + 0x7FFFu + ((u >> 16) & 1u)) >> 16); // RNE
}

// Reflect-padded signal as bf16, row stride XPSTRIDE, tail zero-filled.
__global__ __launch_bounds__(256) void build_xp(const float* __restrict__ x,
                                                unsigned short* __restrict__ xp) {
  const int i = blockIdx.x * 256 + threadIdx.x;   // [0, XPSTRIDE)
  const int b = blockIdx.y;
  unsigned short v = 0;
  if (i < TPAD) {
    int j = i - PAD;
    if (j < 0) j = -j;                             // left reflect
    if (j >= T_LEN) j = 2 * T_LEN - 2 - j;         // right reflect
    v = f2bf(x[(size_t)b * T_LEN + j]);
  }
  xp[(size_t)b * XPSTRIDE + i] = v;
}

// Basis matrix bmat[jcol][k], jcol in [0,1152):
//   jcol = 2f   -> cos(2*pi/1024 * f * k) * w[k]
//   jcol = 2f+1 -> -sin(2*pi/1024 * f * k) * w[k]
// jcol=1024/1025 fall out exactly (f=512 -> (-1)^k, 0); jcol>=1026 -> 0.
__global__ __launch_bounds__(256) void build_bmat(const float* __restrict__ win,
                                                  unsigned short* __restrict__ bm) {
  const int k = blockIdx.x * 256 + threadIdx.x;   // [0,1024)
  const int j = blockIdx.y;                       // [0,1152)
  unsigned short o = 0;
  if (j < NOUTROW) {
    const int f = j >> 1;
    const int r = (f * k) & (KTOT - 1);           // exact arg reduction
    const float ang = (float)r * 6.1359231515e-3f;  // 2*pi/1024
    const float c = __cosf(ang), s = __sinf(ang);
    const float v = (j & 1) ? -s : c;
    o = f2bf(v * win[k]);
  }
  bm[(size_t)j * KTOT + k] = o;
}

// C[m][j] = sum_k xp[b][t*HOP + k] * bmat[j][k]
// Occupancy-first, register-safe: A and B both double-buffered 128x32 LDS
// slices (32 KB total), single barrier per k-iter, staging issued a full
// MFMA-phase before its vmcnt drain. launch_bounds(256,3): 170-reg budget
// fits acc(64 AGPR)+frags(48)+addrs -> 3 blocks/CU (12 waves) vs R3's 2.
__global__ __launch_bounds__(256, 3) void stft_gemm(const unsigned short* __restrict__ xp,
                                                    const unsigned short* __restrict__ bmat,
                                                    float* __restrict__ out) {
  __shared__ unsigned short As[2][BM * BK];   // 2 x 8 KB
  __shared__ unsigned short Bs[2][BN * BK];   // 2 x 8 KB

  const int tid  = threadIdx.x;
  const int lane = tid & 63;
  const int wv   = tid >> 6;
  const int wr   = wv >> 1, wc = wv & 1;   // 2x2 waves over 128x128
  const int bx   = blockIdx.x;             // [0,240)
  const int b    = bx / 15;
  const int t0   = (bx - b * 15) * BM;     // frame base, <=1792
  const int j0   = blockIdx.y * BN;        // [0,1152) step 128
  const int L    = lane & 15;
  const int quad = lane >> 4;

  // Staging sources. Thread owns chunks ci = p*256+tid (16 B each) in BOTH
  // tiles; row/col = ci>>2, stored k-chunk slot = ci&3 holds global k-chunk
  // c = (ci&3)^(row&3)  (XOR swizzle -> frag reads 4-way not 8-way aliased).
  const unsigned short* asrc[2];
  const unsigned short* bsrc[2];
#pragma unroll
  for (int p = 0; p < 2; ++p) {
    const int ci  = p * 256 + tid;
    const int row = ci >> 2;
    const int c   = (ci & 3) ^ (row & 3);
    asrc[p] = xp + (size_t)b * XPSTRIDE + (size_t)(t0 + row) * HOP + c * 8;
    bsrc[p] = bmat + (size_t)(j0 + row) * KTOT + c * 8;
  }

  // Fragment LDS element offsets (swizzled slot = quad ^ (row&3), row&3 == L&3)
  int aoff[4], boff[4];
#pragma unroll
  for (int t = 0; t < 4; ++t) {
    const int m = wr * 64 + t * 16 + L;
    aoff[t] = m * BK + (quad ^ (m & 3)) * 8;
    const int n = wc * 64 + t * 16 + L;
    boff[t] = n * BK + (quad ^ (n & 3)) * 8;
  }

  floatx4 acc[4][4] = {};

  auto stage = [&](int buf, int kk) {
#pragma unroll
    for (int p = 0; p < 2; ++p) {
      const int ci = p * 256 + tid;
      __builtin_amdgcn_global_load_lds(
          (const __attribute__((address_space(1))) void*)(asrc[p] + kk),
          (__attribute__((address_space(3))) void*)((char*)As[buf] + ci * 16),
          16, 0, 0);
      __builtin_amdgcn_global_load_lds(
          (const __attribute__((address_space(1))) void*)(bsrc[p] + kk),
          (__attribute__((address_space(3))) void*)((char*)Bs[buf] + ci * 16),
          16, 0, 0);
    }
  };

  // ---- prologue ----
  stage(0, 0);
  __syncthreads();

  // ---- main loop: ONE barrier per BK step; staging drains at the barrier,
  //      ~310 MFMA cycles after issue (latency hidden) ----
  for (int k0 = 0; k0 < KTOT; k0 += BK) {
    const int buf = (k0 >> 5) & 1;
    if (k0 + BK < KTOT) stage(buf ^ 1, k0 + BK);

    short8 af[4], bf[4];
#pragma unroll
    for (int t = 0; t < 4; ++t) {
      af[t] = *(const short8*)&As[buf][aoff[t]];
      bf[t] = *(const short8*)&Bs[buf][boff[t]];
    }
#pragma unroll
    for (int ti = 0; ti < 4; ++ti)
#pragma unroll
      for (int tj = 0; tj < 4; ++tj)
        acc[ti][tj] = __builtin_amdgcn_mfma_f32_16x16x32_bf16(
            af[ti], bf[tj], acc[ti][tj], 0, 0, 0);

    __syncthreads();   // waves done reading buf; staging to buf^1 drained
  }

  // ---- epilogue: D[row = quad*4 + i][col = L] per 16x16 tile ----
#pragma unroll
  for (int ti = 0; ti < 4; ++ti) {
    const int tb = t0 + wr * 64 + ti * 16 + quad * 4;
#pragma unroll
    for (int tj = 0; tj < 4; ++tj) {
      const int gj = j0 + wc * 64 + tj * 16 + L;
      if (gj < NOUTROW) {
#pragma unroll
        for (int i = 0; i < 4; ++i) {
          const int t = tb + i;
          if (t < NFRAMES)
            out[(size_t)(b * NFRAMES + t) * NOUTROW + gj] = acc[ti][tj][i];
        }
      }
    }
  }
}

extern "C" void kernel_launch(void* const* d_in, const int* in_sizes, int n_in,
                              void* d_out, int out_size, void* d_ws, size_t ws_size,
                              hipStream_t stream) {
  const float* x   = (const float*)d_in[0];   // (16, 480000) fp32
  const float* win = (const float*)d_in[1];   // (1024,) fp32
  float* out = (float*)d_out;                 // (16, 1876, 513, 2) fp32

  unsigned short* xp   = (unsigned short*)d_ws;                  // 16*493568 bf16 = 15.8 MB
  unsigned short* bmat = xp + (size_t)BATCH * XPSTRIDE;          // 1152*1024 bf16 = 2.36 MB

  build_xp  <<<dim3(XPSTRIDE / 256, BATCH), 256, 0, stream>>>(x, xp);
  build_bmat<<<dim3(KTOT / 256, NCOLS),     256, 0, stream>>>(win, bmat);
  stft_gemm <<<dim3(BATCH * (FRPAD / BM), NCOLS / BN), 256, 0, stream>>>(xp, bmat, out);
}